// Round 8
// baseline (740.018 us; speedup 1.0000x reference)
//
#include <hip/hip_runtime.h>

// TensorProductWithScalarComponents: out[s,w',k] = c * sum_{u,v} Wc[(u,v),w'] * x[s,u,k]*y[s,v]
// Wc = Wt . Wl folded on device, packed in MFMA-B fragment order (f16), K-order kc = u*2+vh.
// Staged GEMM: 512-thread blocks (8 waves as 4M x 2N). B double-buffered in LDS via
// global_load_lds (16KB chunks), each fragment read by 4 waves (N-split halves LDS traffic).
// x staged in LDS as DUPLICATED f16 pairs (dword per element, 20-dword row stride:
// conflict-free reads+writes, no broadcast inst in A-build). y in registers.
// f16 MFMA 16x16x32; pow2 path-norm applied in f32 epilogue.

typedef _Float16 f16x8 __attribute__((ext_vector_type(8)));
typedef _Float16 h2    __attribute__((ext_vector_type(2)));
typedef float    f32x4 __attribute__((ext_vector_type(4)));

__device__ __forceinline__ void gload_lds16(const void* g, void* l) {
    __builtin_amdgcn_global_load_lds(
        (const __attribute__((address_space(1))) unsigned*)g,
        (__attribute__((address_space(3))) unsigned*)l, 16, 0, 0);
}

// ---------------- prologue: fold Wl into Wt, pack into MFMA-B fragment layout (f16) ----------
// (kc, nt, lane, j) <-> (u = kc>>1, vh = kc&1, v = vh*32 + (lane>>4)*8 + j, w' = nt*16 + (lane&15))
// stored at Bp[((kc*NT + nt)*64 + lane)*8 + j]   (K-order: u outer, vh inner)
template<int M, int NT>
__global__ void pack_b(const float* __restrict__ Wt, const float* __restrict__ Wl,
                       _Float16* __restrict__ Bp) {
    const int gid = blockIdx.x * 256 + threadIdx.x;
    const int total = M * 64 * M / 2;
    if (gid >= total) return;
    const int w_ = gid & (M - 1);            // output channel w'
    const int uvp = gid / M;                 // uv pair index
    const float4* wtA = (const float4*)(Wt + (size_t)(2 * uvp) * M);
    const float4* wtB = (const float4*)(Wt + (size_t)(2 * uvp + 1) * M);
    float a0 = 0.f, a1 = 0.f;
    #pragma unroll 4
    for (int w = 0; w < M; w += 4) {
        float4 tA = wtA[w >> 2], tB = wtB[w >> 2];
        float l0 = Wl[(w + 0) * M + w_], l1 = Wl[(w + 1) * M + w_];
        float l2 = Wl[(w + 2) * M + w_], l3 = Wl[(w + 3) * M + w_];
        a0 += tA.x * l0 + tA.y * l1 + tA.z * l2 + tA.w * l3;
        a1 += tB.x * l0 + tB.y * l1 + tB.z * l2 + tB.w * l3;
    }
    #pragma unroll
    for (int t = 0; t < 2; ++t) {
        const int uv = 2 * uvp + t;
        const int u = uv >> 6, v = uv & 63;
        const int vh = v >> 5, vv = v & 31, quad = vv >> 3, j = vv & 7;
        const int kc = u * 2 + vh, nt = w_ >> 4, lane = quad * 16 + (w_ & 15);
        Bp[((size_t)(kc * NT + nt) * 64 + lane) * 8 + j] = (_Float16)(t ? a1 : a0);
    }
}

// ---------------- main fused staged GEMM ----------------
template<int M, int NCOMP, int XOFF, int NT, int KC, int MT>
__device__ __forceinline__ void tp_block(char* smem, int wg,
    const float* __restrict__ x, const float* __restrict__ y,
    const _Float16* __restrict__ Bp, float* __restrict__ out, int Rtot, float cscale)
{
    constexpr int WAVES_M = 4, WAVES_N = 2;       // 8 waves = 4M x 2N
    constexpr int WM = MT / (WAVES_M * 16);       // row frags per wave (6 or 8)
    constexpr int WN = NT / WAVES_N;              // B frags per wave (B shared via LDS)
    constexpr int UC = KC / 2;                    // u's per B chunk
    constexpr int XU = 16;                        // u's per x slab
    constexpr int XS = 20;                        // x row stride in DWORDS (pair-dup layout)
    constexpr int KTOT = 2 * M;
    constexpr int NCHUNK = KTOT / KC;
    constexpr int CPS = XU / UC;                  // chunks per x slab
    constexpr int NSLAB = M / XU;
    constexpr int BCH = KC * NT * 1024;           // B chunk bytes (=16384 for all three)
    constexpr int XSL = MT * XS * 4;              // x slab bytes
    constexpr int NS_T = MT / NCOMP + 2;          // samples touched by a tile (upper bound)
    constexpr int XE = NS_T * XU * NCOMP;         // x elements per slab
    constexpr int XITER = (XE + 511) / 512;

    char* bb0 = smem;
    char* bb1 = smem + BCH;
    char* xb0 = smem + 2 * BCH;
    char* xb1 = smem + 2 * BCH + XSL;

    const int tid = threadIdx.x;
    const int lane = tid & 63;
    const int wv = tid >> 6;
    const int wvn = wv & 1;                       // N-half
    const int wvm = wv >> 1;                      // M-quarter
    const int l15 = lane & 15;
    const int quad = lane >> 4;
    const int r0 = wg * MT;
    const int s0 = r0 / NCOMP;
    const int k0 = r0 - s0 * NCOMP;

    float xt[XITER];
    auto xld = [&](int slab) {            // issue x global loads for a slab into registers
        const int ub = slab * XU;
        #pragma unroll
        for (int i = 0; i < XITER; ++i) {
            const int p = tid + i * 512;
            float v = 0.f;
            if (p < XE) {
                const int sl = p / (XU * NCOMP);
                const int fo = p - sl * (XU * NCOMP);
                const int ul = fo / NCOMP;
                const int k  = fo - ul * NCOMP;
                const int rl = sl * NCOMP + k - k0;
                if (rl >= 0 && rl < MT && (r0 + rl) < Rtot)
                    v = x[(size_t)(s0 + sl) * 480 + XOFF + (ub + ul) * NCOMP + k];
            }
            xt[i] = v;
        }
    };
    auto xwr = [&](char* xd) {            // cvt + duplicate-pair LDS write (dword per element)
        #pragma unroll
        for (int i = 0; i < XITER; ++i) {
            const int p = tid + i * 512;
            if (p < XE) {
                const int sl = p / (XU * NCOMP);
                const int fo = p - sl * (XU * NCOMP);
                const int ul = fo / NCOMP;
                const int k  = fo - ul * NCOMP;
                const int rl = sl * NCOMP + k - k0;
                if (rl >= 0 && rl < MT) {
                    union { _Float16 h; unsigned short u; } cv; cv.h = (_Float16)xt[i];
                    const unsigned pp = (unsigned)cv.u | ((unsigned)cv.u << 16);
                    *(unsigned*)(xd + (unsigned)((rl * XS + ul) << 2)) = pp;
                }
            }
        }
    };
    auto stageB = [&](int c, char* bd) {  // 2 x global_load_lds_dwordx4 per wave = 16KB/block
        const char* gs = (const char*)Bp + (size_t)c * BCH + wv * 2048 + lane * 16;
        char* ld = bd + wv * 2048;
        gload_lds16(gs, ld);
        gload_lds16(gs + 1024, ld + 1024);
    };

    // y -> registers once per block (both v-halves), f32 -> packed f16 pairs
    int rowf[WM];
    union YH { f16x8 v; h2 h[4]; };
    YH yh[2][WM];
    #pragma unroll
    for (int f = 0; f < WM; ++f) {
        rowf[f] = wvm * (WM * 16) + f * 16 + l15;
        const int Rg = r0 + rowf[f];
        const int sf = (Rg < Rtot) ? (int)((unsigned)Rg / NCOMP) : 0;
        #pragma unroll
        for (int vh = 0; vh < 2; ++vh) {
            const float4* yp = (const float4*)(y + (size_t)sf * 64 + vh * 32 + quad * 8);
            const float4 a = yp[0], b = yp[1];
            union { f16x8 v; _Float16 e[8]; } t;
            t.e[0] = (_Float16)a.x; t.e[1] = (_Float16)a.y;
            t.e[2] = (_Float16)a.z; t.e[3] = (_Float16)a.w;
            t.e[4] = (_Float16)b.x; t.e[5] = (_Float16)b.y;
            t.e[6] = (_Float16)b.z; t.e[7] = (_Float16)b.w;
            yh[vh][f].v = t.v;
        }
    }

    f32x4 acc[WM][WN];
    #pragma unroll
    for (int f = 0; f < WM; ++f)
        #pragma unroll
        for (int g = 0; g < WN; ++g) acc[f][g] = f32x4{0.f, 0.f, 0.f, 0.f};

    // prologue: slab 0 + chunk 0
    xld(0);
    stageB(0, bb0);
    xwr(xb0);
    __syncthreads();

    int bcur = 0, xcur = 0;
    #pragma unroll 1
    for (int c = 0; c < NCHUNK; ++c) {
        if (c + 1 < NCHUNK) stageB(c + 1, bcur ? bb0 : bb1);
        const int cm = c & (CPS - 1);
        const int sl1 = c / CPS + 1;
        if (cm == 0 && sl1 < NSLAB) xld(sl1);

        const char* bs = bcur ? bb1 : bb0;
        const char* xs = xcur ? xb1 : xb0;
        const int uoff = cm * UC;

        uint4 xv[WM];                      // UC duplicated x pairs per row frag
        #pragma unroll
        for (int f = 0; f < WM; ++f) {
            const char* xa = xs + (unsigned)((rowf[f] * XS + uoff) << 2);
            if constexpr (UC == 1)      { xv[f].x = *(const unsigned*)xa; }
            else if constexpr (UC == 2) { const uint2 t = *(const uint2*)xa; xv[f].x = t.x; xv[f].y = t.y; }
            else                        { xv[f] = *(const uint4*)xa; }
        }
        #pragma unroll
        for (int kl = 0; kl < KC; ++kl) {
            const int vh = kl & 1, uo = kl >> 1;
            f16x8 bg[WN];
            #pragma unroll
            for (int g = 0; g < WN; ++g)
                bg[g] = *(const f16x8*)(bs + (unsigned)((kl * NT + wvn * WN + g) << 10) + lane * 16);
            f16x8 af[WM];
            #pragma unroll
            for (int f = 0; f < WM; ++f) {
                const unsigned px = (uo == 0) ? xv[f].x : (uo == 1) ? xv[f].y
                                  : (uo == 2) ? xv[f].z : xv[f].w;
                union { unsigned u; h2 h; } xb2; xb2.u = px;   // already duplicated pair
                union { f16x8 v; h2 h[4]; } a_;
                #pragma unroll
                for (int q = 0; q < 4; ++q) a_.h[q] = xb2.h * yh[vh][f].h[q];
                af[f] = a_.v;
            }
            #pragma unroll
            for (int f = 0; f < WM; ++f)
                #pragma unroll
                for (int g = 0; g < WN; ++g)
                    acc[f][g] = __builtin_amdgcn_mfma_f32_16x16x32_f16(af[f], bg[g], acc[f][g], 0, 0, 0);
        }
        if (cm == CPS - 1 && sl1 < NSLAB) xwr(xcur ? xb0 : xb1);
        __syncthreads();
        bcur ^= 1;
        if (cm == CPS - 1) xcur ^= 1;
    }

    // epilogue: C/D layout col = lane&15, row = quad*4 + reg (m89-verified); pow2 scale in f32
    #pragma unroll
    for (int f = 0; f < WM; ++f) {
        #pragma unroll
        for (int g = 0; g < WN; ++g) {
            const int col = (wvn * WN + g) * 16 + l15;   // w'
            #pragma unroll
            for (int r = 0; r < 4; ++r) {
                const int R = r0 + wvm * (WM * 16) + f * 16 + quad * 4 + r;
                if (R < Rtot) {
                    const int s = (int)((unsigned)R / NCOMP);
                    const int k = R - s * NCOMP;
                    out[(size_t)s * 480 + XOFF + col * NCOMP + k] = acc[f][g][r] * cscale;
                }
            }
        }
    }
}

__global__ __launch_bounds__(512, 2)
void tp_main(const float* __restrict__ x, const float* __restrict__ y,
             const _Float16* __restrict__ B0, const _Float16* __restrict__ B1,
             const _Float16* __restrict__ B2, float* __restrict__ out,
             int R0, int R1, int R2, int G0, int G1)
{
    // LDS: B 2x16KB + x 2x(MT*20*4): l0 = 32768+61440 = 94208; l1/l2 = 32768+81920 = 114688
    __shared__ char smem[114688];
    const int b = blockIdx.x;
    if (b < G0)            tp_block<128, 1,   0, 8, 2, 384>(smem, b,           x, y, B0, out, R0, 1.f / 1024.f);
    else if (b < G0 + G1)  tp_block< 64, 3, 128, 4, 4, 512>(smem, b - G0,      x, y, B1, out, R1, 1.f / 512.f);
    else                   tp_block< 32, 5, 320, 2, 8, 512>(smem, b - G0 - G1, x, y, B2, out, R2, 1.f / 256.f);
}

extern "C" void kernel_launch(void* const* d_in, const int* in_sizes, int n_in,
                              void* d_out, int out_size, void* d_ws, size_t ws_size,
                              hipStream_t stream) {
    const float* x   = (const float*)d_in[0];
    const float* y   = (const float*)d_in[1];
    const float* Wt0 = (const float*)d_in[2];
    const float* Wl0 = (const float*)d_in[3];
    const float* Wt1 = (const float*)d_in[4];
    const float* Wl1 = (const float*)d_in[5];
    const float* Wt2 = (const float*)d_in[6];
    const float* Wl2 = (const float*)d_in[7];
    float* out = (float*)d_out;

    const int Ns = in_sizes[0] / 480;

    _Float16* B0 = (_Float16*)d_ws;                    // 8192x128 f16 = 2 MiB
    _Float16* B1 = B0 + 8192 * 128;                    // 4096x64  = 512 KiB
    _Float16* B2 = B1 + 4096 * 64;                     // 2048x32  = 128 KiB

    pack_b<128, 8><<<(128 * 64 * 128 / 2 + 255) / 256, 256, 0, stream>>>(Wt0, Wl0, B0);
    pack_b< 64, 4><<<( 64 * 64 *  64 / 2 + 255) / 256, 256, 0, stream>>>(Wt1, Wl1, B1);
    pack_b< 32, 2><<<( 32 * 64 *  32 / 2 + 255) / 256, 256, 0, stream>>>(Wt2, Wl2, B2);

    const int R0 = Ns, R1 = Ns * 3, R2 = Ns * 5;
    const int G0 = (R0 + 383) / 384;
    const int G1 = (R1 + 511) / 512;
    const int G2 = (R2 + 511) / 512;
    tp_main<<<G0 + G1 + G2, 512, 0, stream>>>(x, y, B0, B1, B2, out, R0, R1, R2, G0, G1);
}

// Round 9
// 736.403 us; speedup vs baseline: 1.0049x; 1.0049x over previous
//
#include <hip/hip_runtime.h>

// TensorProductWithScalarComponents: out[s,w',k] = c * sum_{u,v} Wc[(u,v),w'] * x[s,u,k]*y[s,v]
// Wc = Wt . Wl folded on device, packed in MFMA-B fragment order (f16), K-order kc = vh*M + u
// (vh OUTER: a chunk spans one v-half -> y register state halved; y reloaded at half-K).
// Staged GEMM: 512-thread blocks (8 waves as 4M x 2N). B double-buffered in LDS via
// global_load_lds (16KB chunks). x staged per-8-u slab as DUPLICATED f16 pairs
// (dword/element, 12-dword row stride: 16B-aligned rows, conflict-free, no broadcast inst).
// f16 MFMA 16x16x32; pow2 path-norm applied in f32 epilogue.

typedef _Float16 f16x8 __attribute__((ext_vector_type(8)));
typedef _Float16 h2    __attribute__((ext_vector_type(2)));
typedef float    f32x4 __attribute__((ext_vector_type(4)));

__device__ __forceinline__ void gload_lds16(const void* g, void* l) {
    __builtin_amdgcn_global_load_lds(
        (const __attribute__((address_space(1))) unsigned*)g,
        (__attribute__((address_space(3))) unsigned*)l, 16, 0, 0);
}

// ---------------- prologue: fold Wl into Wt, pack into MFMA-B fragment layout (f16) ----------
// (kc, nt, lane, j) <-> (u = kc%M, vh = kc/M, v = vh*32 + (lane>>4)*8 + j, w' = nt*16 + (lane&15))
// stored at Bp[((kc*NT + nt)*64 + lane)*8 + j]   (K-order: vh outer, u inner)
template<int M, int NT>
__global__ void pack_b(const float* __restrict__ Wt, const float* __restrict__ Wl,
                       _Float16* __restrict__ Bp) {
    const int gid = blockIdx.x * 256 + threadIdx.x;
    const int total = M * 64 * M / 2;
    if (gid >= total) return;
    const int w_ = gid & (M - 1);            // output channel w'
    const int uvp = gid / M;                 // uv pair index
    const float4* wtA = (const float4*)(Wt + (size_t)(2 * uvp) * M);
    const float4* wtB = (const float4*)(Wt + (size_t)(2 * uvp + 1) * M);
    float a0 = 0.f, a1 = 0.f;
    #pragma unroll 4
    for (int w = 0; w < M; w += 4) {
        float4 tA = wtA[w >> 2], tB = wtB[w >> 2];
        float l0 = Wl[(w + 0) * M + w_], l1 = Wl[(w + 1) * M + w_];
        float l2 = Wl[(w + 2) * M + w_], l3 = Wl[(w + 3) * M + w_];
        a0 += tA.x * l0 + tA.y * l1 + tA.z * l2 + tA.w * l3;
        a1 += tB.x * l0 + tB.y * l1 + tB.z * l2 + tB.w * l3;
    }
    #pragma unroll
    for (int t = 0; t < 2; ++t) {
        const int uv = 2 * uvp + t;
        const int u = uv >> 6, v = uv & 63;
        const int vh = v >> 5, vv = v & 31, quad = vv >> 3, j = vv & 7;
        const int kc = vh * M + u, nt = w_ >> 4, lane = quad * 16 + (w_ & 15);
        Bp[((size_t)(kc * NT + nt) * 64 + lane) * 8 + j] = (_Float16)(t ? a1 : a0);
    }
}

// ---------------- main fused staged GEMM ----------------
template<int M, int NCOMP, int XOFF, int NT, int KC, int MT>
__device__ __forceinline__ void tp_block(char* smem, int wg,
    const float* __restrict__ x, const float* __restrict__ y,
    const _Float16* __restrict__ Bp, float* __restrict__ out, int Rtot, float cscale)
{
    constexpr int WM = MT / 64;            // 4 M-waves: row frags per wave (6 or 8)
    constexpr int WN = NT / 2;             // 2 N-waves: B frags per wave
    constexpr int XU = 8;                  // u's per x slab (small: keeps xt regs low)
    constexpr int XS = 12;                 // x row stride in DWORDS (48B, 16B-aligned rows)
    constexpr int KTOT = 2 * M;
    constexpr int NCHUNK = KTOT / KC;
    constexpr int HC = NCHUNK / 2;         // chunks per vh-half
    constexpr int CPS = XU / KC;           // chunks per slab (4 / 2 / 1)
    constexpr int NSLAB = M / XU;          // slabs per vh-half (pow2)
    constexpr int BCH = KC * NT * 1024;    // B chunk bytes (16 KiB for all three)
    constexpr int XSL = MT * XS * 4;       // x slab bytes
    constexpr int NS_T = MT / NCOMP + 2;   // samples touched by a tile (upper bound)
    constexpr int XE = NS_T * XU * NCOMP;  // x elements per slab
    constexpr int XITER = (XE + 511) / 512;
    constexpr int RW = (KC < 4) ? KC : 4;  // x dwords per inner read (2 or 4)
    constexpr int NRW = KC / RW;

    char* bb0 = smem;
    char* bb1 = smem + BCH;
    char* xb0 = smem + 2 * BCH;
    char* xb1 = smem + 2 * BCH + XSL;

    const int tid = threadIdx.x;
    const int lane = tid & 63;
    const int wv = tid >> 6;
    const int wvn = wv & 1;                // N-half
    const int wvm = wv >> 1;               // M-quarter
    const int l15 = lane & 15;
    const int quad = lane >> 4;
    const int r0 = wg * MT;
    const int s0 = r0 / NCOMP;
    const int k0 = r0 - s0 * NCOMP;

    float xt[XITER];
    auto xld = [&](int slab) {             // issue x global loads for a slab into registers
        const int ub = slab * XU;
        #pragma unroll
        for (int i = 0; i < XITER; ++i) {
            const int p = tid + i * 512;
            float v = 0.f;
            if (p < XE) {
                const int sl = p / (XU * NCOMP);
                const int fo = p - sl * (XU * NCOMP);
                const int ul = fo / NCOMP;
                const int k  = fo - ul * NCOMP;
                const int rl = sl * NCOMP + k - k0;
                if (rl >= 0 && rl < MT && (r0 + rl) < Rtot)
                    v = x[(size_t)(s0 + sl) * 480 + XOFF + (ub + ul) * NCOMP + k];
            }
            xt[i] = v;
        }
    };
    auto xwr = [&](char* xd) {             // cvt + duplicate-pair LDS write (dword/element)
        #pragma unroll
        for (int i = 0; i < XITER; ++i) {
            const int p = tid + i * 512;
            if (p < XE) {
                const int sl = p / (XU * NCOMP);
                const int fo = p - sl * (XU * NCOMP);
                const int ul = fo / NCOMP;
                const int k  = fo - ul * NCOMP;
                const int rl = sl * NCOMP + k - k0;
                if (rl >= 0 && rl < MT) {
                    union { _Float16 h; unsigned short u; } cv; cv.h = (_Float16)xt[i];
                    const unsigned pp = (unsigned)cv.u | ((unsigned)cv.u << 16);
                    *(unsigned*)(xd + (unsigned)((rl * XS + ul) << 2)) = pp;
                }
            }
        }
    };
    auto stageB = [&](int c, char* bd) {   // 2 x global_load_lds_dwordx4 per wave = 16KB/block
        const char* gs = (const char*)Bp + (size_t)c * BCH + wv * 2048 + lane * 16;
        char* ld = bd + wv * 2048;
        gload_lds16(gs, ld);
        gload_lds16(gs + 1024, ld + 1024);
    };

    // per-fragment row/sample indices; y fragments (CURRENT v-half only) in registers
    int rowf[WM], sfr[WM];
    #pragma unroll
    for (int f = 0; f < WM; ++f) {
        rowf[f] = wvm * (WM * 16) + f * 16 + l15;
        const int Rg = r0 + rowf[f];
        sfr[f] = (Rg < Rtot) ? (int)((unsigned)Rg / NCOMP) : 0;
    }
    union YH { f16x8 v; h2 h[4]; };
    YH yh[WM];
    auto loady = [&](int vh) {
        #pragma unroll
        for (int f = 0; f < WM; ++f) {
            const float4* yp = (const float4*)(y + (size_t)sfr[f] * 64 + vh * 32 + quad * 8);
            const float4 a = yp[0], b = yp[1];
            union { f16x8 v; _Float16 e[8]; } t;
            t.e[0] = (_Float16)a.x; t.e[1] = (_Float16)a.y;
            t.e[2] = (_Float16)a.z; t.e[3] = (_Float16)a.w;
            t.e[4] = (_Float16)b.x; t.e[5] = (_Float16)b.y;
            t.e[6] = (_Float16)b.z; t.e[7] = (_Float16)b.w;
            yh[f].v = t.v;
        }
    };

    f32x4 acc[WM][WN];
    #pragma unroll
    for (int f = 0; f < WM; ++f)
        #pragma unroll
        for (int g = 0; g < WN; ++g) acc[f][g] = f32x4{0.f, 0.f, 0.f, 0.f};

    // prologue: slab 0 + chunk 0 + y(vh=0)
    xld(0);
    stageB(0, bb0);
    xwr(xb0);
    loady(0);
    __syncthreads();

    int bcur = 0, xcur = 0, nsl = 1;
    #pragma unroll 1
    for (int c = 0; c < NCHUNK; ++c) {
        if (c + 1 < NCHUNK) stageB(c + 1, bcur ? bb0 : bb1);
        const int cm = c & (CPS - 1);
        if (cm == 0 && c + CPS < NCHUNK) { xld(nsl & (NSLAB - 1)); ++nsl; }
        if (c == HC) loady(1);             // second v-half: refresh y regs (L2-hot, once)

        const char* bs = bcur ? bb1 : bb0;
        const char* xs = xcur ? xb1 : xb0;

        #pragma unroll
        for (int rw = 0; rw < NRW; ++rw) {
            unsigned xv[WM][RW];           // duplicated x pairs, static-indexed
            #pragma unroll
            for (int f = 0; f < WM; ++f) {
                const char* xa = xs + (unsigned)((rowf[f] * XS + cm * KC + rw * RW) << 2);
                if constexpr (RW == 2) {
                    const uint2 t = *(const uint2*)xa; xv[f][0] = t.x; xv[f][1] = t.y;
                } else {
                    const uint4 t = *(const uint4*)xa;
                    xv[f][0] = t.x; xv[f][1] = t.y; xv[f][2] = t.z; xv[f][3] = t.w;
                }
            }
            #pragma unroll
            for (int kk = 0; kk < RW; ++kk) {
                const int kl = rw * RW + kk;
                f16x8 bg[WN];
                #pragma unroll
                for (int g = 0; g < WN; ++g)
                    bg[g] = *(const f16x8*)(bs + (unsigned)(((kl * NT + wvn * WN + g) << 10) + lane * 16));
                f16x8 af[WM];
                #pragma unroll
                for (int f = 0; f < WM; ++f) {
                    union { unsigned u; h2 h; } xb2; xb2.u = xv[f][kk];
                    union { f16x8 v; h2 h[4]; } a_;
                    #pragma unroll
                    for (int q = 0; q < 4; ++q) a_.h[q] = xb2.h * yh[f].h[q];
                    af[f] = a_.v;
                }
                #pragma unroll
                for (int f = 0; f < WM; ++f)
                    #pragma unroll
                    for (int g = 0; g < WN; ++g)
                        acc[f][g] = __builtin_amdgcn_mfma_f32_16x16x32_f16(af[f], bg[g], acc[f][g], 0, 0, 0);
            }
        }
        if (cm == CPS - 1 && c + 1 < NCHUNK) xwr(xcur ? xb0 : xb1);
        __syncthreads();
        bcur ^= 1;
        if (cm == CPS - 1) xcur ^= 1;
    }

    // epilogue: C/D layout col = lane&15, row = quad*4 + reg (m89-verified); pow2 scale in f32
    #pragma unroll
    for (int f = 0; f < WM; ++f) {
        #pragma unroll
        for (int g = 0; g < WN; ++g) {
            const int col = (wvn * WN + g) * 16 + l15;   // w'
            #pragma unroll
            for (int r = 0; r < 4; ++r) {
                const int R = r0 + wvm * (WM * 16) + f * 16 + quad * 4 + r;
                if (R < Rtot) {
                    const int s = (int)((unsigned)R / NCOMP);
                    const int k = R - s * NCOMP;
                    out[(size_t)s * 480 + XOFF + col * NCOMP + k] = acc[f][g][r] * cscale;
                }
            }
        }
    }
}

__global__ __launch_bounds__(512, 2)
void tp_main(const float* __restrict__ x, const float* __restrict__ y,
             const _Float16* __restrict__ B0, const _Float16* __restrict__ B1,
             const _Float16* __restrict__ B2, float* __restrict__ out,
             int R0, int R1, int R2, int G0, int G1)
{
    // LDS: B 2x16KB + x 2x(MT*12*4): l0 = 32768+36864 = 69632; l1/l2 = 32768+49152 = 81920
    __shared__ char smem[81920];
    const int b = blockIdx.x;
    if (b < G0)            tp_block<128, 1,   0, 8, 2, 384>(smem, b,           x, y, B0, out, R0, 1.f / 1024.f);
    else if (b < G0 + G1)  tp_block< 64, 3, 128, 4, 4, 512>(smem, b - G0,      x, y, B1, out, R1, 1.f / 512.f);
    else                   tp_block< 32, 5, 320, 2, 8, 512>(smem, b - G0 - G1, x, y, B2, out, R2, 1.f / 256.f);
}

extern "C" void kernel_launch(void* const* d_in, const int* in_sizes, int n_in,
                              void* d_out, int out_size, void* d_ws, size_t ws_size,
                              hipStream_t stream) {
    const float* x   = (const float*)d_in[0];
    const float* y   = (const float*)d_in[1];
    const float* Wt0 = (const float*)d_in[2];
    const float* Wl0 = (const float*)d_in[3];
    const float* Wt1 = (const float*)d_in[4];
    const float* Wl1 = (const float*)d_in[5];
    const float* Wt2 = (const float*)d_in[6];
    const float* Wl2 = (const float*)d_in[7];
    float* out = (float*)d_out;

    const int Ns = in_sizes[0] / 480;

    _Float16* B0 = (_Float16*)d_ws;                    // 8192x128 f16 = 2 MiB
    _Float16* B1 = B0 + 8192 * 128;                    // 4096x64  = 512 KiB
    _Float16* B2 = B1 + 4096 * 64;                     // 2048x32  = 128 KiB

    pack_b<128, 8><<<(128 * 64 * 128 / 2 + 255) / 256, 256, 0, stream>>>(Wt0, Wl0, B0);
    pack_b< 64, 4><<<( 64 * 64 *  64 / 2 + 255) / 256, 256, 0, stream>>>(Wt1, Wl1, B1);
    pack_b< 32, 2><<<( 32 * 64 *  32 / 2 + 255) / 256, 256, 0, stream>>>(Wt2, Wl2, B2);

    const int R0 = Ns, R1 = Ns * 3, R2 = Ns * 5;
    const int G0 = (R0 + 383) / 384;
    const int G1 = (R1 + 511) / 512;
    const int G2 = (R2 + 511) / 512;
    tp_main<<<G0 + G1 + G2, 512, 0, stream>>>(x, y, B0, B1, B2, out, R0, R1, R2, G0, G1);
}